// Round 4
// baseline (353.004 us; speedup 1.0000x reference)
//
#include <hip/hip_runtime.h>
#include <math.h>

#define B_ 16
#define H_ 16
#define M_ 256
#define N_ 576
#define D_ 1024
#define BK 64
#define LDS_STRIDE (BK + 8)
#define NROWS (B_ * N_ + B_ * M_)   // 13312 feature rows to normalize

constexpr float EPS_ = 1e-8f;
constexpr float FI_ = 0.90909090909090906f;   // RHO/(RHO+EPSILON) = 1/1.1

typedef __bf16 bf16x8 __attribute__((ext_vector_type(8)));
typedef float f32x4 __attribute__((ext_vector_type(4)));

__device__ __forceinline__ float wave_reduce(float v) {
#pragma unroll
  for (int o = 32; o > 0; o >>= 1) v += __shfl_down(v, o, 64);
  return v;
}

__device__ __forceinline__ unsigned short f2bf(float f) {
  union { float f; unsigned u; } a; a.f = f;
  unsigned r = a.u + 0x7fff + ((a.u >> 16) & 1);   // RNE
  return (unsigned short)(r >> 16);
}

__device__ __forceinline__ float bf2f(unsigned short u) {
  union { unsigned u; float f; } a; a.u = ((unsigned)u) << 16;
  return a.f;
}

// One launch: L2-normalize+bf16-cast vis (B*N rows) and txt (B*M rows), one wave
// per row; trailing 4 blocks compute masksum[b] = sum_m mask[b,m].
__global__ __launch_bounds__(256) void prep_kernel(const float* __restrict__ vis,
                                                   const float* __restrict__ txt,
                                                   const float* __restrict__ mask,
                                                   unsigned short* __restrict__ xb,
                                                   unsigned short* __restrict__ yb,
                                                   float* __restrict__ masksum) {
  const int bid = blockIdx.x;
  const int lane = threadIdx.x & 63;
  if (bid < NROWS / 4) {
    int wave = bid * 4 + (threadIdx.x >> 6);
    const float* src;
    unsigned short* dst;
    if (wave < B_ * N_) {
      src = vis + (size_t)wave * D_;
      dst = xb + (size_t)wave * D_;
    } else {
      int r = wave - B_ * N_;
      src = txt + (size_t)r * D_;
      dst = yb + (size_t)r * D_;
    }
    float4 v[4];
    float s = 0.f;
#pragma unroll
    for (int it = 0; it < 4; ++it) {
      v[it] = *(const float4*)&src[it * 256 + lane * 4];
      s += v[it].x * v[it].x + v[it].y * v[it].y + v[it].z * v[it].z + v[it].w * v[it].w;
    }
    s = wave_reduce(s);
    s = __shfl(s, 0, 64);
    float inv = rsqrtf(s + 1e-12f);
#pragma unroll
    for (int it = 0; it < 4; ++it) {
      ushort4 pk;
      pk.x = f2bf(v[it].x * inv);
      pk.y = f2bf(v[it].y * inv);
      pk.z = f2bf(v[it].z * inv);
      pk.w = f2bf(v[it].w * inv);
      *(ushort4*)&dst[it * 256 + lane * 4] = pk;
    }
  } else {
    int b = (bid - NROWS / 4) * 4 + (threadIdx.x >> 6);  // 0..15
    float4 mv = *(const float4*)&mask[b * M_ + lane * 4];
    float s = wave_reduce(mv.x + mv.y + mv.z + mv.w);
    if (lane == 0) masksum[b] = s;
  }
}

// K[b,m,n] = bf16(exp(10*(dot(yb[b,m],xb[b,n]) - 1))), bf16 MFMA 16x16x32,
// 64x64 tile/block, 4 waves each computing a 32x32 sub-tile (2x2 frags).
__global__ __launch_bounds__(256) void gemm_k_mfma(const unsigned short* __restrict__ xb,
                                                   const unsigned short* __restrict__ yb,
                                                   unsigned short* __restrict__ Kw) {
  __shared__ unsigned short As[64][LDS_STRIDE];  // y rows (m)
  __shared__ unsigned short Bs[64][LDS_STRIDE];  // x rows (n)
  const int b = blockIdx.z;
  const int m0 = blockIdx.y * 64;
  const int n0 = blockIdx.x * 64;
  const unsigned short* Y = yb + (size_t)b * M_ * D_;
  const unsigned short* X = xb + (size_t)b * N_ * D_;
  const int t = threadIdx.x;
  const int lane = t & 63;
  const int w = t >> 6;
  const int wm = (w & 1) * 32;
  const int wn = (w >> 1) * 32;
  const int lr = t >> 3;           // 0..31 staging row
  const int lc = (t & 7) * 8;      // staging col (bf16 units, 16B chunks)
  const int fr = lane & 15;        // fragment row within 16
  const int fk = (lane >> 4) * 8;  // fragment k offset

  f32x4 acc[2][2] = {};
  for (int k0 = 0; k0 < D_; k0 += BK) {
#pragma unroll
    for (int p = 0; p < 2; ++p) {
      *(uint4*)&As[lr + 32 * p][lc] = *(const uint4*)&Y[(size_t)(m0 + lr + 32 * p) * D_ + k0 + lc];
      *(uint4*)&Bs[lr + 32 * p][lc] = *(const uint4*)&X[(size_t)(n0 + lr + 32 * p) * D_ + k0 + lc];
    }
    __syncthreads();
#pragma unroll
    for (int ks = 0; ks < BK; ks += 32) {
      bf16x8 a[2], bfr[2];
#pragma unroll
      for (int i = 0; i < 2; ++i) {
        a[i] = *(const bf16x8*)&As[wm + i * 16 + fr][ks + fk];
        bfr[i] = *(const bf16x8*)&Bs[wn + i * 16 + fr][ks + fk];
      }
#pragma unroll
      for (int i = 0; i < 2; ++i)
#pragma unroll
        for (int j = 0; j < 2; ++j)
          acc[i][j] = __builtin_amdgcn_mfma_f32_16x16x32_bf16(a[i], bfr[j], acc[i][j], 0, 0, 0);
    }
    __syncthreads();
  }

  // C/D layout: m = (lane>>4)*4 + reg, n = lane&15
  const int cm = (lane >> 4) * 4;
  const int cn = lane & 15;
#pragma unroll
  for (int i = 0; i < 2; ++i)
#pragma unroll
    for (int j = 0; j < 2; ++j)
#pragma unroll
      for (int rg = 0; rg < 4; ++rg) {
        int m = m0 + wm + i * 16 + cm + rg;
        int n = n0 + wn + j * 16 + cn;
        Kw[((size_t)b * M_ + m) * N_ + n] = f2bf(expf(10.f * (acc[i][j][rg] - 1.f)));
      }
}

// ---------- Sinkhorn: wide, shallow launches; K stored bf16 ----------

// first u-step (v == 1): u = (nu / (rowsum(K)+EPS))^fi, nu computed inline.
__global__ __launch_bounds__(256) void sink_u_first(const unsigned short* __restrict__ Kw,
                                                    const float* __restrict__ mask,
                                                    const float* __restrict__ masksum,
                                                    float* __restrict__ u) {
  const int b = blockIdx.y;
  const int row = blockIdx.x * 4 + (threadIdx.x >> 6);
  const int lane = threadIdx.x & 63;
  const unsigned short* rowp = Kw + ((size_t)b * M_ + row) * N_;
  float s = 0.f;
#pragma unroll
  for (int k = 0; k < 9; ++k) s += bf2f(rowp[lane + 64 * k]);
  s = wave_reduce(s);
  if (lane == 0) {
    int idx = b * M_ + row;
    float nu = mask[idx] / (masksum[b] + EPS_);
    u[idx] = powf(nu / (s + EPS_), FI_);
  }
}

// u-step: u = (nu/(K·v + EPS))^fi
__global__ __launch_bounds__(256) void sink_u(const unsigned short* __restrict__ Kw,
                                              const float* __restrict__ v,
                                              const float* __restrict__ mask,
                                              const float* __restrict__ masksum,
                                              float* __restrict__ u) {
  const int b = blockIdx.y;
  const int row = blockIdx.x * 4 + (threadIdx.x >> 6);
  const int lane = threadIdx.x & 63;
  const unsigned short* rowp = Kw + ((size_t)b * M_ + row) * N_;
  const float* vb = v + b * N_;
  float s = 0.f;
#pragma unroll
  for (int k = 0; k < 9; ++k) s += bf2f(rowp[lane + 64 * k]) * vb[lane + 64 * k];
  s = wave_reduce(s);
  if (lane == 0) {
    int idx = b * M_ + row;
    float nu = mask[idx] / (masksum[b] + EPS_);
    u[idx] = powf(nu / (s + EPS_), FI_);
  }
}

// v-step: v = (mu/(K^T·u + EPS))^fi
__global__ __launch_bounds__(256) void sink_v(const unsigned short* __restrict__ Kw,
                                              const float* __restrict__ u,
                                              float* __restrict__ v) {
  __shared__ float part[4][64];
  const int b = blockIdx.y;
  const int n0 = blockIdx.x * 64;
  const int col = n0 + (threadIdx.x & 63);
  const int g = threadIdx.x >> 6;
  const unsigned short* Kb = Kw + (size_t)b * M_ * N_;
  const float* ub = u + b * M_;
  float s = 0.f;
#pragma unroll 8
  for (int m = g * 64; m < (g + 1) * 64; ++m) s += bf2f(Kb[(size_t)m * N_ + col]) * ub[m];
  part[g][threadIdx.x & 63] = s;
  __syncthreads();
  if (threadIdx.x < 64) {
    float tot = part[0][threadIdx.x] + part[1][threadIdx.x] +
                part[2][threadIdx.x] + part[3][threadIdx.x];
    v[b * N_ + n0 + threadIdx.x] = powf((1.f / (float)N_) / (tot + EPS_), FI_);
  }
}

// Fused scale+loss. One block per (b,m). u cancels in P's row normalization:
// P[m,n] = K[m,n]*v[n] / (sum_n K[m,n]*v[n] + EPS/u) ~= kv[n]/(Kv+EPS).
// loss += -mask[b,m]/(Kv+EPS) * sum_{h,n} kv[n]*log(student[b,h,m,n]+EPS)
__global__ __launch_bounds__(256) void loss_fused(const float* __restrict__ student,
                                                  const unsigned short* __restrict__ Kw,
                                                  const float* __restrict__ v,
                                                  const float* __restrict__ mask,
                                                  float* __restrict__ out) {
  __shared__ float kv[N_];
  __shared__ float red[4];
  __shared__ float sh_scale;
  const int m = blockIdx.x;
  const int b = blockIdx.y;
  const int t = threadIdx.x;

  const unsigned short* rowp = Kw + ((size_t)b * M_ + m) * N_;
  const float* vb = v + b * N_;
  float part = 0.f;
  for (int i = t; i < N_; i += 256) {
    float val = bf2f(rowp[i]) * vb[i];
    kv[i] = val;
    part += val;
  }
  part = wave_reduce(part);
  if ((t & 63) == 0) red[t >> 6] = part;
  __syncthreads();
  if (t == 0) {
    float Kv = red[0] + red[1] + red[2] + red[3];
    sh_scale = mask[b * M_ + m] / (Kv + EPS_);
  }

  const float* st = student + ((size_t)b * H_ * M_ + m) * N_;
  float acc = 0.f;
#pragma unroll 1
  for (int i = t; i < H_ * (N_ / 4); i += 256) {   // 16*144 = 2304 items
    int h = i / (N_ / 4);
    int n4 = i - h * (N_ / 4);
    float4 s4 = *(const float4*)&st[(size_t)h * M_ * N_ + n4 * 4];
    float4 k4 = *(const float4*)&kv[n4 * 4];
    acc -= k4.x * __logf(s4.x + EPS_) + k4.y * __logf(s4.y + EPS_) +
           k4.z * __logf(s4.z + EPS_) + k4.w * __logf(s4.w + EPS_);
  }
  acc = wave_reduce(acc);
  __syncthreads();          // red[] reuse
  if ((t & 63) == 0) red[t >> 6] = acc;
  __syncthreads();
  if (t == 0) {
    float tot = red[0] + red[1] + red[2] + red[3];
    atomicAdd(out, sh_scale * tot * (1.f / ((float)B_ * H_ * M_)));
  }
}

extern "C" void kernel_launch(void* const* d_in, const int* in_sizes, int n_in,
                              void* d_out, int out_size, void* d_ws, size_t ws_size,
                              hipStream_t stream) {
  const float* student = (const float*)d_in[0];  // (B,H,M,N)
  const float* vis = (const float*)d_in[1];      // (B,N,D)
  const float* txt = (const float*)d_in[2];      // (B,M,D)
  const float* mask = (const float*)d_in[3];     // (B,M)
  float* out = (float*)d_out;

  char* p = (char*)d_ws;
  unsigned short* Kb = (unsigned short*)p; p += (size_t)B_ * M_ * N_ * 2;   // 4.7 MB
  unsigned short* xb = (unsigned short*)p; p += (size_t)B_ * N_ * D_ * 2;   // 18.9 MB
  unsigned short* yb = (unsigned short*)p; p += (size_t)B_ * M_ * D_ * 2;   // 8.4 MB
  float* vv = (float*)p;      p += B_ * N_ * 4;
  float* uu = (float*)p;      p += B_ * M_ * 4;
  float* msum = (float*)p;    p += B_ * 4;

  hipMemsetAsync(d_out, 0, sizeof(float), stream);
  prep_kernel<<<NROWS / 4 + 4, 256, 0, stream>>>(vis, txt, mask, xb, yb, msum);
  gemm_k_mfma<<<dim3(N_ / 64, M_ / 64, B_), 256, 0, stream>>>(xb, yb, Kb);

  sink_u_first<<<dim3(M_ / 4, B_), 256, 0, stream>>>(Kb, mask, msum, uu);
  sink_v<<<dim3(N_ / 64, B_), 256, 0, stream>>>(Kb, uu, vv);
  for (int it = 1; it < 5; ++it) {
    sink_u<<<dim3(M_ / 4, B_), 256, 0, stream>>>(Kb, vv, mask, msum, uu);
    sink_v<<<dim3(N_ / 64, B_), 256, 0, stream>>>(Kb, uu, vv);
  }

  loss_fused<<<dim3(M_, B_), 256, 0, stream>>>(student, Kb, vv, mask, out);
}

// Round 5
// 335.595 us; speedup vs baseline: 1.0519x; 1.0519x over previous
//
#include <hip/hip_runtime.h>
#include <math.h>

#define B_ 16
#define H_ 16
#define M_ 256
#define N_ 576
#define D_ 1024
#define BK 64
#define LDS_STRIDE (BK + 8)
#define NROWS (B_ * N_ + B_ * M_)   // 13312 feature rows to normalize

constexpr float EPS_ = 1e-8f;
constexpr float FI_ = 0.90909090909090906f;   // RHO/(RHO+EPSILON) = 1/1.1

typedef __bf16 bf16x8 __attribute__((ext_vector_type(8)));
typedef float f32x4 __attribute__((ext_vector_type(4)));

__device__ __forceinline__ float wave_reduce(float v) {
#pragma unroll
  for (int o = 32; o > 0; o >>= 1) v += __shfl_down(v, o, 64);
  return v;
}

__device__ __forceinline__ unsigned short f2bf(float f) {
  union { float f; unsigned u; } a; a.f = f;
  unsigned r = a.u + 0x7fff + ((a.u >> 16) & 1);   // RNE
  return (unsigned short)(r >> 16);
}

__device__ __forceinline__ float bf2f(unsigned short u) {
  union { unsigned u; float f; } a; a.u = ((unsigned)u) << 16;
  return a.f;
}

// SL[b,m,n] = sum_h log(student[b,h,m,n]+EPS). Pure streaming, no deps.
// One block per (m,b); threads 0..143 own a float4 column group.
__global__ __launch_bounds__(256) void sumlog_kernel(const float* __restrict__ student,
                                                     float* __restrict__ SL) {
  const int m = blockIdx.x;
  const int b = blockIdx.y;
  const int t = threadIdx.x;
  if (t >= N_ / 4) return;
  const float* st = student + ((size_t)b * H_ * M_ + m) * N_ + t * 4;
  float4 acc = {0.f, 0.f, 0.f, 0.f};
#pragma unroll
  for (int h = 0; h < H_; ++h) {
    float4 s4 = *(const float4*)&st[(size_t)h * M_ * N_];
    acc.x += __logf(s4.x + EPS_);
    acc.y += __logf(s4.y + EPS_);
    acc.z += __logf(s4.z + EPS_);
    acc.w += __logf(s4.w + EPS_);
  }
  *(float4*)&SL[((size_t)b * M_ + m) * N_ + t * 4] = acc;
}

// One launch: L2-normalize+bf16-cast vis (B*N rows) and txt (B*M rows), one wave
// per row; trailing 4 blocks compute masksum[b] = sum_m mask[b,m].
__global__ __launch_bounds__(256) void prep_kernel(const float* __restrict__ vis,
                                                   const float* __restrict__ txt,
                                                   const float* __restrict__ mask,
                                                   unsigned short* __restrict__ xb,
                                                   unsigned short* __restrict__ yb,
                                                   float* __restrict__ masksum) {
  const int bid = blockIdx.x;
  const int lane = threadIdx.x & 63;
  if (bid < NROWS / 4) {
    int wave = bid * 4 + (threadIdx.x >> 6);
    const float* src;
    unsigned short* dst;
    if (wave < B_ * N_) {
      src = vis + (size_t)wave * D_;
      dst = xb + (size_t)wave * D_;
    } else {
      int r = wave - B_ * N_;
      src = txt + (size_t)r * D_;
      dst = yb + (size_t)r * D_;
    }
    float4 v[4];
    float s = 0.f;
#pragma unroll
    for (int it = 0; it < 4; ++it) {
      v[it] = *(const float4*)&src[it * 256 + lane * 4];
      s += v[it].x * v[it].x + v[it].y * v[it].y + v[it].z * v[it].z + v[it].w * v[it].w;
    }
    s = wave_reduce(s);
    s = __shfl(s, 0, 64);
    float inv = rsqrtf(s + 1e-12f);
#pragma unroll
    for (int it = 0; it < 4; ++it) {
      ushort4 pk;
      pk.x = f2bf(v[it].x * inv);
      pk.y = f2bf(v[it].y * inv);
      pk.z = f2bf(v[it].z * inv);
      pk.w = f2bf(v[it].w * inv);
      *(ushort4*)&dst[it * 256 + lane * 4] = pk;
    }
  } else {
    int b = (bid - NROWS / 4) * 4 + (threadIdx.x >> 6);  // 0..15
    float4 mv = *(const float4*)&mask[b * M_ + lane * 4];
    float s = wave_reduce(mv.x + mv.y + mv.z + mv.w);
    if (lane == 0) masksum[b] = s;
  }
}

// K[b,m,n] = bf16(exp(10*(dot(yb[b,m],xb[b,n]) - 1))), bf16 MFMA 16x16x32,
// 64x64 tile/block, 4 waves each computing a 32x32 sub-tile (2x2 frags).
__global__ __launch_bounds__(256) void gemm_k_mfma(const unsigned short* __restrict__ xb,
                                                   const unsigned short* __restrict__ yb,
                                                   unsigned short* __restrict__ Kw) {
  __shared__ unsigned short As[64][LDS_STRIDE];  // y rows (m)
  __shared__ unsigned short Bs[64][LDS_STRIDE];  // x rows (n)
  const int b = blockIdx.z;
  const int m0 = blockIdx.y * 64;
  const int n0 = blockIdx.x * 64;
  const unsigned short* Y = yb + (size_t)b * M_ * D_;
  const unsigned short* X = xb + (size_t)b * N_ * D_;
  const int t = threadIdx.x;
  const int lane = t & 63;
  const int w = t >> 6;
  const int wm = (w & 1) * 32;
  const int wn = (w >> 1) * 32;
  const int lr = t >> 3;           // 0..31 staging row
  const int lc = (t & 7) * 8;      // staging col (bf16 units, 16B chunks)
  const int fr = lane & 15;        // fragment row within 16
  const int fk = (lane >> 4) * 8;  // fragment k offset

  f32x4 acc[2][2] = {};
  for (int k0 = 0; k0 < D_; k0 += BK) {
#pragma unroll
    for (int p = 0; p < 2; ++p) {
      *(uint4*)&As[lr + 32 * p][lc] = *(const uint4*)&Y[(size_t)(m0 + lr + 32 * p) * D_ + k0 + lc];
      *(uint4*)&Bs[lr + 32 * p][lc] = *(const uint4*)&X[(size_t)(n0 + lr + 32 * p) * D_ + k0 + lc];
    }
    __syncthreads();
#pragma unroll
    for (int ks = 0; ks < BK; ks += 32) {
      bf16x8 a[2], bfr[2];
#pragma unroll
      for (int i = 0; i < 2; ++i) {
        a[i] = *(const bf16x8*)&As[wm + i * 16 + fr][ks + fk];
        bfr[i] = *(const bf16x8*)&Bs[wn + i * 16 + fr][ks + fk];
      }
#pragma unroll
      for (int i = 0; i < 2; ++i)
#pragma unroll
        for (int j = 0; j < 2; ++j)
          acc[i][j] = __builtin_amdgcn_mfma_f32_16x16x32_bf16(a[i], bfr[j], acc[i][j], 0, 0, 0);
    }
    __syncthreads();
  }

  // C/D layout: m = (lane>>4)*4 + reg, n = lane&15
  const int cm = (lane >> 4) * 4;
  const int cn = lane & 15;
#pragma unroll
  for (int i = 0; i < 2; ++i)
#pragma unroll
    for (int j = 0; j < 2; ++j)
#pragma unroll
      for (int rg = 0; rg < 4; ++rg) {
        int m = m0 + wm + i * 16 + cm + rg;
        int n = n0 + wn + j * 16 + cn;
        Kw[((size_t)b * M_ + m) * N_ + n] = f2bf(expf(10.f * (acc[i][j][rg] - 1.f)));
      }
}

// ---------- Sinkhorn: wide, shallow launches; K stored bf16 ----------

// first u-step (v == 1): u = (nu / (rowsum(K)+EPS))^fi, nu computed inline.
__global__ __launch_bounds__(256) void sink_u_first(const unsigned short* __restrict__ Kw,
                                                    const float* __restrict__ mask,
                                                    const float* __restrict__ masksum,
                                                    float* __restrict__ u) {
  const int b = blockIdx.y;
  const int row = blockIdx.x * 4 + (threadIdx.x >> 6);
  const int lane = threadIdx.x & 63;
  const unsigned short* rowp = Kw + ((size_t)b * M_ + row) * N_;
  float s = 0.f;
#pragma unroll
  for (int k = 0; k < 9; ++k) s += bf2f(rowp[lane + 64 * k]);
  s = wave_reduce(s);
  if (lane == 0) {
    int idx = b * M_ + row;
    float nu = mask[idx] / (masksum[b] + EPS_);
    u[idx] = powf(nu / (s + EPS_), FI_);
  }
}

// u-step: u = (nu/(K·v + EPS))^fi
__global__ __launch_bounds__(256) void sink_u(const unsigned short* __restrict__ Kw,
                                              const float* __restrict__ v,
                                              const float* __restrict__ mask,
                                              const float* __restrict__ masksum,
                                              float* __restrict__ u) {
  const int b = blockIdx.y;
  const int row = blockIdx.x * 4 + (threadIdx.x >> 6);
  const int lane = threadIdx.x & 63;
  const unsigned short* rowp = Kw + ((size_t)b * M_ + row) * N_;
  const float* vb = v + b * N_;
  float s = 0.f;
#pragma unroll
  for (int k = 0; k < 9; ++k) s += bf2f(rowp[lane + 64 * k]) * vb[lane + 64 * k];
  s = wave_reduce(s);
  if (lane == 0) {
    int idx = b * M_ + row;
    float nu = mask[idx] / (masksum[b] + EPS_);
    u[idx] = powf(nu / (s + EPS_), FI_);
  }
}

// v-step: v = (mu/(K^T·u + EPS))^fi
__global__ __launch_bounds__(256) void sink_v(const unsigned short* __restrict__ Kw,
                                              const float* __restrict__ u,
                                              float* __restrict__ v) {
  __shared__ float part[4][64];
  const int b = blockIdx.y;
  const int n0 = blockIdx.x * 64;
  const int col = n0 + (threadIdx.x & 63);
  const int g = threadIdx.x >> 6;
  const unsigned short* Kb = Kw + (size_t)b * M_ * N_;
  const float* ub = u + b * M_;
  float s = 0.f;
#pragma unroll 8
  for (int m = g * 64; m < (g + 1) * 64; ++m) s += bf2f(Kb[(size_t)m * N_ + col]) * ub[m];
  part[g][threadIdx.x & 63] = s;
  __syncthreads();
  if (threadIdx.x < 64) {
    float tot = part[0][threadIdx.x] + part[1][threadIdx.x] +
                part[2][threadIdx.x] + part[3][threadIdx.x];
    v[b * N_ + n0 + threadIdx.x] = powf((1.f / (float)N_) / (tot + EPS_), FI_);
  }
}

// Per (b,m) row: s1 = sum_n K*v, s2 = sum_n K*v*SL.
// partial[row] = -mask[row]*s2 / ((s1+EPS)*B*H*M).  (u cancels in row-norm.)
__global__ __launch_bounds__(256) void finloss_kernel(const unsigned short* __restrict__ Kw,
                                                      const float* __restrict__ SL,
                                                      const float* __restrict__ v,
                                                      const float* __restrict__ mask,
                                                      float* __restrict__ partial) {
  __shared__ float red[2][4];
  const int m = blockIdx.x;
  const int b = blockIdx.y;
  const int t = threadIdx.x;
  float s1 = 0.f, s2 = 0.f;
  if (t < N_ / 4) {
    const unsigned short* kp = Kw + ((size_t)b * M_ + m) * N_ + t * 4;
    ushort4 k4 = *(const ushort4*)kp;
    float4 v4 = *(const float4*)&v[b * N_ + t * 4];
    float4 sl4 = *(const float4*)&SL[((size_t)b * M_ + m) * N_ + t * 4];
    float kv0 = bf2f(k4.x) * v4.x, kv1 = bf2f(k4.y) * v4.y;
    float kv2 = bf2f(k4.z) * v4.z, kv3 = bf2f(k4.w) * v4.w;
    s1 = kv0 + kv1 + kv2 + kv3;
    s2 = kv0 * sl4.x + kv1 * sl4.y + kv2 * sl4.z + kv3 * sl4.w;
  }
  s1 = wave_reduce(s1);
  s2 = wave_reduce(s2);
  if ((t & 63) == 0) { red[0][t >> 6] = s1; red[1][t >> 6] = s2; }
  __syncthreads();
  if (t == 0) {
    float S1 = red[0][0] + red[0][1] + red[0][2] + red[0][3];
    float S2 = red[1][0] + red[1][1] + red[1][2] + red[1][3];
    int row = b * M_ + m;
    partial[row] = -mask[row] * S2 / ((S1 + EPS_) * (float)(B_ * H_ * M_));
  }
}

// Sum 4096 partials -> d_out[0]. Single block.
__global__ __launch_bounds__(256) void reduce_kernel(const float* __restrict__ partial,
                                                     float* __restrict__ out) {
  __shared__ float red[4];
  float s = 0.f;
  for (int i = threadIdx.x; i < B_ * M_; i += 256) s += partial[i];
  s = wave_reduce(s);
  if ((threadIdx.x & 63) == 0) red[threadIdx.x >> 6] = s;
  __syncthreads();
  if (threadIdx.x == 0) out[0] = red[0] + red[1] + red[2] + red[3];
}

extern "C" void kernel_launch(void* const* d_in, const int* in_sizes, int n_in,
                              void* d_out, int out_size, void* d_ws, size_t ws_size,
                              hipStream_t stream) {
  const float* student = (const float*)d_in[0];  // (B,H,M,N)
  const float* vis = (const float*)d_in[1];      // (B,N,D)
  const float* txt = (const float*)d_in[2];      // (B,M,D)
  const float* mask = (const float*)d_in[3];     // (B,M)
  float* out = (float*)d_out;

  char* p = (char*)d_ws;
  unsigned short* Kb = (unsigned short*)p; p += (size_t)B_ * M_ * N_ * 2;   // 4.7 MB
  unsigned short* xb = (unsigned short*)p; p += (size_t)B_ * N_ * D_ * 2;   // 18.9 MB
  unsigned short* yb = (unsigned short*)p; p += (size_t)B_ * M_ * D_ * 2;   // 8.4 MB
  float* SL = (float*)p;      p += (size_t)B_ * M_ * N_ * 4;                // 9.4 MB
  float* vv = (float*)p;      p += B_ * N_ * 4;
  float* uu = (float*)p;      p += B_ * M_ * 4;
  float* msum = (float*)p;    p += B_ * 4;
  float* partial = (float*)p; p += B_ * M_ * 4;

  // Independent 151 MB streaming reduction first.
  sumlog_kernel<<<dim3(M_, B_), 256, 0, stream>>>(student, SL);

  prep_kernel<<<NROWS / 4 + 4, 256, 0, stream>>>(vis, txt, mask, xb, yb, msum);
  gemm_k_mfma<<<dim3(N_ / 64, M_ / 64, B_), 256, 0, stream>>>(xb, yb, Kb);

  sink_u_first<<<dim3(M_ / 4, B_), 256, 0, stream>>>(Kb, mask, msum, uu);
  sink_v<<<dim3(N_ / 64, B_), 256, 0, stream>>>(Kb, uu, vv);
  for (int it = 1; it < 5; ++it) {
    sink_u<<<dim3(M_ / 4, B_), 256, 0, stream>>>(Kb, vv, mask, msum, uu);
    sink_v<<<dim3(N_ / 64, B_), 256, 0, stream>>>(Kb, uu, vv);
  }

  finloss_kernel<<<dim3(M_, B_), 256, 0, stream>>>(Kb, SL, vv, mask, partial);
  reduce_kernel<<<1, 256, 0, stream>>>(partial, out);
}